// Round 8
// baseline (1115.087 us; speedup 1.0000x reference)
//
#include <hip/hip_runtime.h>
#include <hip/hip_bf16.h>
#include <math.h>

#define BATCH 8192
#define INSZ 784
#define SYS 1024
#define OUTSZ 10
#define NSTEP 100
#define HSTEP 0.01f
#define FFORCE 8.0f

typedef short short8 __attribute__((ext_vector_type(8)));
typedef float float4v __attribute__((ext_vector_type(4)));
typedef float v2f __attribute__((ext_vector_type(2)));

static __device__ __forceinline__ short f2bf(float x) {
    __hip_bfloat16 b = __float2bfloat16(x);   // RNE
    return __builtin_bit_cast(short, b);
}
static __device__ __forceinline__ float bf2f(short s) {
    unsigned int u = ((unsigned int)(unsigned short)s) << 16;
    return __builtin_bit_cast(float, u);
}

static __device__ __forceinline__ v2f pkfma(v2f a, v2f b, v2f c) {
    return __builtin_elementwise_fma(a, b, c);
}
static __device__ __forceinline__ v2f mk2(float x, float y) {
    v2f r; r.x = x; r.y = y; return r;
}
static __device__ __forceinline__ v2f swp(v2f v) {
    return __builtin_shufflevector(v, v, 1, 0);
}
// halo transport on the DS pipe (overlaps with VALU; DPP regressed — r5)
static __device__ __forceinline__ v2f sh2(v2f v, int ln) {
    v2f r; r.x = __shfl(v.x, ln); r.y = __shfl(v.y, ln); return r;
}

// ---------------------------------------------------------------------------
// GEMM1 (unchanged from round 2): h = x @ W1^T + b1, split-bf16 MFMA.
// ---------------------------------------------------------------------------
#define BMg 128
#define BNg 128
#define BKg 32
#define LDK 40

__global__ __launch_bounds__(256, 3) void gemm1_kernel(
    const float* __restrict__ x, const float* __restrict__ W1,
    const float* __restrict__ b1, float* __restrict__ h)
{
    __shared__ short Ah[BMg * LDK], Al[BMg * LDK];
    __shared__ short Bh[BNg * LDK], Bl[BNg * LDK];

    const int t  = threadIdx.x;
    const int bm = blockIdx.y * BMg;
    const int bn = blockIdx.x * BNg;

    const int srow = t >> 1;
    const int kq   = (t & 1) * 16;

    const int wv   = t >> 6;
    const int lane = t & 63;
    const int lm   = lane & 15;
    const int q    = lane >> 4;
    const int rb   = (wv & 1) * 64;
    const int cb   = (wv >> 1) * 64;

    float4v acc[4][4];
    #pragma unroll
    for (int i = 0; i < 4; ++i)
        #pragma unroll
        for (int j = 0; j < 4; ++j) {
            acc[i][j][0] = 0.f; acc[i][j][1] = 0.f;
            acc[i][j][2] = 0.f; acc[i][j][3] = 0.f;
        }

    const float* xa0 = x  + (size_t)(bm + srow) * INSZ + kq;
    const float* wb0 = W1 + (size_t)(bn + srow) * INSZ + kq;

    for (int it = 0; it < 25; ++it) {
        const int k0 = it * BKg;
        {
            const bool valid = (k0 + kq) < INSZ;
            float va[16], vb[16];
            if (valid) {
                #pragma unroll
                for (int p = 0; p < 4; ++p) {
                    float4 xv = ((const float4*)(xa0 + k0))[p];
                    float4 bv = ((const float4*)(wb0 + k0))[p];
                    va[4*p+0] = xv.x; va[4*p+1] = xv.y; va[4*p+2] = xv.z; va[4*p+3] = xv.w;
                    vb[4*p+0] = bv.x; vb[4*p+1] = bv.y; vb[4*p+2] = bv.z; vb[4*p+3] = bv.w;
                }
            } else {
                #pragma unroll
                for (int j = 0; j < 16; ++j) { va[j] = 0.f; vb[j] = 0.f; }
            }
            short8 ahi[2], alo[2], bhi[2], blo[2];
            #pragma unroll
            for (int j = 0; j < 16; ++j) {
                short h1 = f2bf(va[j]);
                short l1 = f2bf(va[j] - bf2f(h1));
                short h2 = f2bf(vb[j]);
                short l2 = f2bf(vb[j] - bf2f(h2));
                ahi[j >> 3][j & 7] = h1;  alo[j >> 3][j & 7] = l1;
                bhi[j >> 3][j & 7] = h2;  blo[j >> 3][j & 7] = l2;
            }
            const int base = srow * LDK + kq;
            *(short8*)&Ah[base] = ahi[0];  *(short8*)&Ah[base + 8] = ahi[1];
            *(short8*)&Al[base] = alo[0];  *(short8*)&Al[base + 8] = alo[1];
            *(short8*)&Bh[base] = bhi[0];  *(short8*)&Bh[base + 8] = bhi[1];
            *(short8*)&Bl[base] = blo[0];  *(short8*)&Bl[base + 8] = blo[1];
        }
        __syncthreads();

        short8 bhf[4], blf[4];
        #pragma unroll
        for (int fj = 0; fj < 4; ++fj) {
            const int off = (cb + fj * 16 + lm) * LDK + q * 8;
            bhf[fj] = *(const short8*)&Bh[off];
            blf[fj] = *(const short8*)&Bl[off];
        }
        #pragma unroll
        for (int fi = 0; fi < 4; ++fi) {
            const int off = (rb + fi * 16 + lm) * LDK + q * 8;
            short8 ah = *(const short8*)&Ah[off];
            short8 al = *(const short8*)&Al[off];
            #pragma unroll
            for (int fj = 0; fj < 4; ++fj) {
                acc[fi][fj] = __builtin_amdgcn_mfma_f32_16x16x32_bf16(ah, bhf[fj], acc[fi][fj], 0, 0, 0);
                acc[fi][fj] = __builtin_amdgcn_mfma_f32_16x16x32_bf16(ah, blf[fj], acc[fi][fj], 0, 0, 0);
                acc[fi][fj] = __builtin_amdgcn_mfma_f32_16x16x32_bf16(al, bhf[fj], acc[fi][fj], 0, 0, 0);
            }
        }
        __syncthreads();
    }

    #pragma unroll
    for (int fj = 0; fj < 4; ++fj) {
        const int col  = bn + cb + fj * 16 + lm;
        const float bias = b1[col];
        #pragma unroll
        for (int fi = 0; fi < 4; ++fi) {
            const int row0 = bm + rb + fi * 16 + q * 4;
            #pragma unroll
            for (int r = 0; r < 4; ++r)
                h[(size_t)(row0 + r) * SYS + col] = acc[fi][fj][r] + bias;
        }
    }
}

// ---------------------------------------------------------------------------
// RK4 Lorenz-96 + GEMM2 + log_softmax; packed fp32, ONE ROW PER WAVE
// (8 waves/SIMD for latency hiding) with the twist pairing:
// pair p = (y[p], y[p+512]), lane n owns pairs 8n..8n+7 (8 v2f state).
// +1 element shift == +1 pair-ring shift with component swap at the wrap
// (cndmask on lanes 0/63 only). Halos issued boundary-first (r7 pipelining),
// transported on the DS pipe.
// ---------------------------------------------------------------------------
__global__ __launch_bounds__(256, 8) void rk4_kernel(
    const float* __restrict__ hbuf, const float* __restrict__ W2,
    const float* __restrict__ b2, float* __restrict__ out)
{
    const int lane = threadIdx.x & 63;
    const int w    = threadIdx.x >> 6;
    const int row  = blockIdx.x * 4 + w;

    const int laneL = (lane + 63) & 63;
    const int laneR = (lane + 1) & 63;
    const bool atL  = (lane == 0);
    const bool atR  = (lane == 63);

    v2f X[8];
    {
        const float4* b4 = (const float4*)(hbuf + (size_t)row * SYS);
        float4 a0 = b4[lane * 2], a1 = b4[lane * 2 + 1];
        float4 c0 = b4[128 + lane * 2], c1 = b4[129 + lane * 2];
        X[0] = mk2(a0.x, c0.x); X[1] = mk2(a0.y, c0.y);
        X[2] = mk2(a0.z, c0.z); X[3] = mk2(a0.w, c0.w);
        X[4] = mk2(a1.x, c1.x); X[5] = mk2(a1.y, c1.y);
        X[6] = mk2(a1.z, c1.z); X[7] = mk2(a1.w, c1.w);
    }

    const v2f Fv     = mk2(FFORCE, FFORCE);
    const v2f c_half = mk2(0.5f * HSTEP, 0.5f * HSTEP);
    const v2f c_full = mk2(HSTEP, HSTEP);
    const v2f c_two  = mk2(2.0f, 2.0f);
    const v2f c_six  = mk2(HSTEP / 6.0f, HSTEP / 6.0f);

    v2f acc[8], T[8];

    // in-place deriv with pre-issued (already-swapped) halos; interior first,
    // DS consumers last.
    auto deriv_ip = [&](v2f (&y)[8], v2f r1, v2f l1, v2f l2) {
        v2f y0o = y[0], y1o = y[1], y2o = y[2];
        v2f d0 = Fv - y[0], d1 = Fv - y[1], d7 = Fv - y[7];
        v2f p2 = y0o, p1 = y1o, cur = y[2];
        #pragma unroll
        for (int i = 2; i < 7; ++i) {
            v2f yp1 = (i < 6) ? y[i + 1] : y[7];
            v2f nv  = pkfma(yp1 - p2, p1, Fv - cur);
            p2 = p1; p1 = cur;
            if (i < 6) cur = y[i + 1];
            y[i] = nv;
        }
        y[7] = pkfma(r1 - p2, p1, d7);        // first DS consume
        y[1] = pkfma(y2o - l1, y0o, d1);
        y[0] = pkfma(y1o - l2, l1, d0);
    };

    // k1 halos on X (swapped where the pair-ring wraps)
    v2f r1x = sh2(X[0], laneR);  r1x = atR ? swp(r1x) : r1x;
    v2f l1x = sh2(X[7], laneL);  l1x = atL ? swp(l1x) : l1x;
    v2f l2x = sh2(X[6], laneL);  l2x = atL ? swp(l2x) : l2x;

    #pragma unroll 1
    for (int s = 0; s < NSTEP; ++s) {
        // ---- k1 = deriv(X) out-of-place into acc (X intact) ----
        #pragma unroll
        for (int i = 2; i < 7; ++i)
            acc[i] = pkfma(X[i + 1] - X[i - 2], X[i - 1], Fv - X[i]);
        acc[7] = pkfma(r1x - X[5], X[6], Fv - X[7]);
        acc[1] = pkfma(X[2] - l1x, X[0],  Fv - X[1]);
        acc[0] = pkfma(X[1] - l2x, l1x,   Fv - X[0]);

        // ---- T = X + h/2*k1 ; boundary first, issue k2 halos ----
        T[6] = pkfma(c_half, acc[6], X[6]);
        T[7] = pkfma(c_half, acc[7], X[7]);
        T[0] = pkfma(c_half, acc[0], X[0]);
        v2f r1 = sh2(T[0], laneR);  r1 = atR ? swp(r1) : r1;
        v2f l1 = sh2(T[7], laneL);  l1 = atL ? swp(l1) : l1;
        v2f l2 = sh2(T[6], laneL);  l2 = atL ? swp(l2) : l2;
        #pragma unroll
        for (int i = 1; i < 6; ++i) T[i] = pkfma(c_half, acc[i], X[i]);
        deriv_ip(T, r1, l1, l2);                        // T = k2

        // ---- acc += 2*k2 ; T = X + h/2*k2 ; boundary first, k3 halos ----
        {
            v2f a;
            a = T[6]; acc[6] = pkfma(c_two, a, acc[6]); T[6] = pkfma(c_half, a, X[6]);
            a = T[7]; acc[7] = pkfma(c_two, a, acc[7]); T[7] = pkfma(c_half, a, X[7]);
            a = T[0]; acc[0] = pkfma(c_two, a, acc[0]); T[0] = pkfma(c_half, a, X[0]);
            r1 = sh2(T[0], laneR);  r1 = atR ? swp(r1) : r1;
            l1 = sh2(T[7], laneL);  l1 = atL ? swp(l1) : l1;
            l2 = sh2(T[6], laneL);  l2 = atL ? swp(l2) : l2;
            #pragma unroll
            for (int i = 1; i < 6; ++i) {
                a = T[i]; acc[i] = pkfma(c_two, a, acc[i]); T[i] = pkfma(c_half, a, X[i]);
            }
        }
        deriv_ip(T, r1, l1, l2);                        // T = k3

        // ---- acc += 2*k3 ; T = X + h*k3 ; boundary first, k4 halos ----
        {
            v2f a;
            a = T[6]; acc[6] = pkfma(c_two, a, acc[6]); T[6] = pkfma(c_full, a, X[6]);
            a = T[7]; acc[7] = pkfma(c_two, a, acc[7]); T[7] = pkfma(c_full, a, X[7]);
            a = T[0]; acc[0] = pkfma(c_two, a, acc[0]); T[0] = pkfma(c_full, a, X[0]);
            r1 = sh2(T[0], laneR);  r1 = atR ? swp(r1) : r1;
            l1 = sh2(T[7], laneL);  l1 = atL ? swp(l1) : l1;
            l2 = sh2(T[6], laneL);  l2 = atL ? swp(l2) : l2;
            #pragma unroll
            for (int i = 1; i < 6; ++i) {
                a = T[i]; acc[i] = pkfma(c_two, a, acc[i]); T[i] = pkfma(c_full, a, X[i]);
            }
        }
        deriv_ip(T, r1, l1, l2);                        // T = k4

        // ---- X += h/6*(acc + k4) ; boundary first, next k1 halos ----
        X[6] = pkfma(c_six, acc[6] + T[6], X[6]);
        X[7] = pkfma(c_six, acc[7] + T[7], X[7]);
        X[0] = pkfma(c_six, acc[0] + T[0], X[0]);
        r1x = sh2(X[0], laneR);  r1x = atR ? swp(r1x) : r1x;
        l1x = sh2(X[7], laneL);  l1x = atL ? swp(l1x) : l1x;
        l2x = sh2(X[6], laneL);  l2x = atL ? swp(l2x) : l2x;
        #pragma unroll
        for (int i = 1; i < 6; ++i)
            X[i] = pkfma(c_six, acc[i] + T[i], X[i]);
    }

    // GEMM2 + log_softmax epilogue (packed dot over (j, j+512), wave reduce)
    float l[OUTSZ];
    #pragma unroll
    for (int o = 0; o < OUTSZ; ++o) {
        const float4* w4 = (const float4*)(W2 + (size_t)o * SYS);
        float4 wa0 = w4[lane * 2], wa1 = w4[lane * 2 + 1];
        float4 wc0 = w4[128 + lane * 2], wc1 = w4[129 + lane * 2];
        v2f s2 = mk2(0.f, 0.f);
        s2 = pkfma(X[0], mk2(wa0.x, wc0.x), s2);
        s2 = pkfma(X[1], mk2(wa0.y, wc0.y), s2);
        s2 = pkfma(X[2], mk2(wa0.z, wc0.z), s2);
        s2 = pkfma(X[3], mk2(wa0.w, wc0.w), s2);
        s2 = pkfma(X[4], mk2(wa1.x, wc1.x), s2);
        s2 = pkfma(X[5], mk2(wa1.y, wc1.y), s2);
        s2 = pkfma(X[6], mk2(wa1.z, wc1.z), s2);
        s2 = pkfma(X[7], mk2(wa1.w, wc1.w), s2);
        float s = s2.x + s2.y;
        #pragma unroll
        for (int dlt = 1; dlt < 64; dlt <<= 1) s += __shfl_xor(s, dlt);
        l[o] = s + b2[o];
    }

    float m = l[0];
    #pragma unroll
    for (int o = 1; o < OUTSZ; ++o) m = fmaxf(m, l[o]);
    float ssum = 0.f;
    #pragma unroll
    for (int o = 0; o < OUTSZ; ++o) ssum += __expf(l[o] - m);
    const float lse = m + __logf(ssum);

    float v = l[0] - lse;
    #pragma unroll
    for (int o = 1; o < OUTSZ; ++o)
        if (lane == o) v = l[o] - lse;
    if (lane < OUTSZ)
        out[(size_t)row * OUTSZ + lane] = v;
}

extern "C" void kernel_launch(void* const* d_in, const int* in_sizes, int n_in,
                              void* d_out, int out_size, void* d_ws, size_t ws_size,
                              hipStream_t stream)
{
    const float* x  = (const float*)d_in[0];
    const float* W1 = (const float*)d_in[1];
    const float* b1 = (const float*)d_in[2];
    const float* W2 = (const float*)d_in[3];
    const float* b2 = (const float*)d_in[4];
    float* out = (float*)d_out;
    float* h   = (float*)d_ws;   // 8192*1024*4 = 33.5 MB scratch

    dim3 g1(SYS / BNg, BATCH / BMg);   // 8 x 64 = 512 blocks
    gemm1_kernel<<<g1, 256, 0, stream>>>(x, W1, b1, h);

    rk4_kernel<<<BATCH / 4, 256, 0, stream>>>(h, W2, b2, out);  // 2048 blocks, 1 row/wave
}

// Round 9
// 474.750 us; speedup vs baseline: 2.3488x; 2.3488x over previous
//
#include <hip/hip_runtime.h>
#include <hip/hip_bf16.h>
#include <math.h>

#define BATCH 8192
#define INSZ 784
#define SYS 1024
#define OUTSZ 10
#define NSTEP 100
#define HSTEP 0.01f
#define FFORCE 8.0f

typedef short short8 __attribute__((ext_vector_type(8)));
typedef float float4v __attribute__((ext_vector_type(4)));
typedef float v2f __attribute__((ext_vector_type(2)));

static __device__ __forceinline__ short f2bf(float x) {
    __hip_bfloat16 b = __float2bfloat16(x);   // RNE
    return __builtin_bit_cast(short, b);
}
static __device__ __forceinline__ float bf2f(short s) {
    unsigned int u = ((unsigned int)(unsigned short)s) << 16;
    return __builtin_bit_cast(float, u);
}

static __device__ __forceinline__ v2f pkfma(v2f a, v2f b, v2f c) {
    return __builtin_elementwise_fma(a, b, c);
}
static __device__ __forceinline__ v2f mk2(float x, float y) {
    v2f r; r.x = x; r.y = y; return r;
}
static __device__ __forceinline__ v2f swp(v2f v) {
    return __builtin_shufflevector(v, v, 1, 0);
}
// halo transport on the DS pipe (overlaps with VALU; DPP regressed — r5)
static __device__ __forceinline__ v2f sh2(v2f v, int ln) {
    v2f r; r.x = __shfl(v.x, ln); r.y = __shfl(v.y, ln); return r;
}

// ---------------------------------------------------------------------------
// GEMM1 (unchanged from round 2): h = x @ W1^T + b1, split-bf16 MFMA.
// ---------------------------------------------------------------------------
#define BMg 128
#define BNg 128
#define BKg 32
#define LDK 40

__global__ __launch_bounds__(256, 3) void gemm1_kernel(
    const float* __restrict__ x, const float* __restrict__ W1,
    const float* __restrict__ b1, float* __restrict__ h)
{
    __shared__ short Ah[BMg * LDK], Al[BMg * LDK];
    __shared__ short Bh[BNg * LDK], Bl[BNg * LDK];

    const int t  = threadIdx.x;
    const int bm = blockIdx.y * BMg;
    const int bn = blockIdx.x * BNg;

    const int srow = t >> 1;
    const int kq   = (t & 1) * 16;

    const int wv   = t >> 6;
    const int lane = t & 63;
    const int lm   = lane & 15;
    const int q    = lane >> 4;
    const int rb   = (wv & 1) * 64;
    const int cb   = (wv >> 1) * 64;

    float4v acc[4][4];
    #pragma unroll
    for (int i = 0; i < 4; ++i)
        #pragma unroll
        for (int j = 0; j < 4; ++j) {
            acc[i][j][0] = 0.f; acc[i][j][1] = 0.f;
            acc[i][j][2] = 0.f; acc[i][j][3] = 0.f;
        }

    const float* xa0 = x  + (size_t)(bm + srow) * INSZ + kq;
    const float* wb0 = W1 + (size_t)(bn + srow) * INSZ + kq;

    for (int it = 0; it < 25; ++it) {
        const int k0 = it * BKg;
        {
            const bool valid = (k0 + kq) < INSZ;
            float va[16], vb[16];
            if (valid) {
                #pragma unroll
                for (int p = 0; p < 4; ++p) {
                    float4 xv = ((const float4*)(xa0 + k0))[p];
                    float4 bv = ((const float4*)(wb0 + k0))[p];
                    va[4*p+0] = xv.x; va[4*p+1] = xv.y; va[4*p+2] = xv.z; va[4*p+3] = xv.w;
                    vb[4*p+0] = bv.x; vb[4*p+1] = bv.y; vb[4*p+2] = bv.z; vb[4*p+3] = bv.w;
                }
            } else {
                #pragma unroll
                for (int j = 0; j < 16; ++j) { va[j] = 0.f; vb[j] = 0.f; }
            }
            short8 ahi[2], alo[2], bhi[2], blo[2];
            #pragma unroll
            for (int j = 0; j < 16; ++j) {
                short h1 = f2bf(va[j]);
                short l1 = f2bf(va[j] - bf2f(h1));
                short h2 = f2bf(vb[j]);
                short l2 = f2bf(vb[j] - bf2f(h2));
                ahi[j >> 3][j & 7] = h1;  alo[j >> 3][j & 7] = l1;
                bhi[j >> 3][j & 7] = h2;  blo[j >> 3][j & 7] = l2;
            }
            const int base = srow * LDK + kq;
            *(short8*)&Ah[base] = ahi[0];  *(short8*)&Ah[base + 8] = ahi[1];
            *(short8*)&Al[base] = alo[0];  *(short8*)&Al[base + 8] = alo[1];
            *(short8*)&Bh[base] = bhi[0];  *(short8*)&Bh[base + 8] = bhi[1];
            *(short8*)&Bl[base] = blo[0];  *(short8*)&Bl[base + 8] = blo[1];
        }
        __syncthreads();

        short8 bhf[4], blf[4];
        #pragma unroll
        for (int fj = 0; fj < 4; ++fj) {
            const int off = (cb + fj * 16 + lm) * LDK + q * 8;
            bhf[fj] = *(const short8*)&Bh[off];
            blf[fj] = *(const short8*)&Bl[off];
        }
        #pragma unroll
        for (int fi = 0; fi < 4; ++fi) {
            const int off = (rb + fi * 16 + lm) * LDK + q * 8;
            short8 ah = *(const short8*)&Ah[off];
            short8 al = *(const short8*)&Al[off];
            #pragma unroll
            for (int fj = 0; fj < 4; ++fj) {
                acc[fi][fj] = __builtin_amdgcn_mfma_f32_16x16x32_bf16(ah, bhf[fj], acc[fi][fj], 0, 0, 0);
                acc[fi][fj] = __builtin_amdgcn_mfma_f32_16x16x32_bf16(ah, blf[fj], acc[fi][fj], 0, 0, 0);
                acc[fi][fj] = __builtin_amdgcn_mfma_f32_16x16x32_bf16(al, bhf[fj], acc[fi][fj], 0, 0, 0);
            }
        }
        __syncthreads();
    }

    #pragma unroll
    for (int fj = 0; fj < 4; ++fj) {
        const int col  = bn + cb + fj * 16 + lm;
        const float bias = b1[col];
        #pragma unroll
        for (int fi = 0; fi < 4; ++fi) {
            const int row0 = bm + rb + fi * 16 + q * 4;
            #pragma unroll
            for (int r = 0; r < 4; ++r)
                h[(size_t)(row0 + r) * SYS + col] = acc[fi][fj][r] + bias;
        }
    }
}

// ---------------------------------------------------------------------------
// RK4 Lorenz-96 + GEMM2 + log_softmax; packed fp32, ONE ROW PER WAVE with
// the twist pairing: pair p = (y[p], y[p+512]), lane n owns pairs 8n..8n+7.
// Grid supplies 8 waves/SIMD; __launch_bounds__(256,4) only (r8's (256,8)
// forced VGPR=32 -> scratch spill, 108 MB writes, 3.6x regression).
// Actual VGPR ~56-64 allows full 8-wave residency without spilling.
// ---------------------------------------------------------------------------
__global__ __launch_bounds__(256, 4) void rk4_kernel(
    const float* __restrict__ hbuf, const float* __restrict__ W2,
    const float* __restrict__ b2, float* __restrict__ out)
{
    const int lane = threadIdx.x & 63;
    const int w    = threadIdx.x >> 6;
    const int row  = blockIdx.x * 4 + w;

    const int laneL = (lane + 63) & 63;
    const int laneR = (lane + 1) & 63;
    const bool atL  = (lane == 0);
    const bool atR  = (lane == 63);

    v2f X[8];
    {
        const float4* b4 = (const float4*)(hbuf + (size_t)row * SYS);
        float4 a0 = b4[lane * 2], a1 = b4[lane * 2 + 1];
        float4 c0 = b4[128 + lane * 2], c1 = b4[129 + lane * 2];
        X[0] = mk2(a0.x, c0.x); X[1] = mk2(a0.y, c0.y);
        X[2] = mk2(a0.z, c0.z); X[3] = mk2(a0.w, c0.w);
        X[4] = mk2(a1.x, c1.x); X[5] = mk2(a1.y, c1.y);
        X[6] = mk2(a1.z, c1.z); X[7] = mk2(a1.w, c1.w);
    }

    const v2f Fv     = mk2(FFORCE, FFORCE);
    const v2f c_half = mk2(0.5f * HSTEP, 0.5f * HSTEP);
    const v2f c_full = mk2(HSTEP, HSTEP);
    const v2f c_two  = mk2(2.0f, 2.0f);
    const v2f c_six  = mk2(HSTEP / 6.0f, HSTEP / 6.0f);

    v2f acc[8], T[8];

    // in-place deriv with pre-issued (already-swapped) halos; interior first,
    // DS consumers last.
    auto deriv_ip = [&](v2f (&y)[8], v2f r1, v2f l1, v2f l2) {
        v2f y0o = y[0], y1o = y[1], y2o = y[2];
        v2f d0 = Fv - y[0], d1 = Fv - y[1], d7 = Fv - y[7];
        v2f p2 = y0o, p1 = y1o, cur = y[2];
        #pragma unroll
        for (int i = 2; i < 7; ++i) {
            v2f yp1 = (i < 6) ? y[i + 1] : y[7];
            v2f nv  = pkfma(yp1 - p2, p1, Fv - cur);
            p2 = p1; p1 = cur;
            if (i < 6) cur = y[i + 1];
            y[i] = nv;
        }
        y[7] = pkfma(r1 - p2, p1, d7);        // first DS consume
        y[1] = pkfma(y2o - l1, y0o, d1);
        y[0] = pkfma(y1o - l2, l1, d0);
    };

    // k1 halos on X (swapped where the pair-ring wraps)
    v2f r1x = sh2(X[0], laneR);  r1x = atR ? swp(r1x) : r1x;
    v2f l1x = sh2(X[7], laneL);  l1x = atL ? swp(l1x) : l1x;
    v2f l2x = sh2(X[6], laneL);  l2x = atL ? swp(l2x) : l2x;

    #pragma unroll 1
    for (int s = 0; s < NSTEP; ++s) {
        // ---- k1 = deriv(X) out-of-place into acc (X intact) ----
        #pragma unroll
        for (int i = 2; i < 7; ++i)
            acc[i] = pkfma(X[i + 1] - X[i - 2], X[i - 1], Fv - X[i]);
        acc[7] = pkfma(r1x - X[5], X[6], Fv - X[7]);
        acc[1] = pkfma(X[2] - l1x, X[0],  Fv - X[1]);
        acc[0] = pkfma(X[1] - l2x, l1x,   Fv - X[0]);

        // ---- T = X + h/2*k1 ; boundary first, issue k2 halos ----
        T[6] = pkfma(c_half, acc[6], X[6]);
        T[7] = pkfma(c_half, acc[7], X[7]);
        T[0] = pkfma(c_half, acc[0], X[0]);
        v2f r1 = sh2(T[0], laneR);  r1 = atR ? swp(r1) : r1;
        v2f l1 = sh2(T[7], laneL);  l1 = atL ? swp(l1) : l1;
        v2f l2 = sh2(T[6], laneL);  l2 = atL ? swp(l2) : l2;
        #pragma unroll
        for (int i = 1; i < 6; ++i) T[i] = pkfma(c_half, acc[i], X[i]);
        deriv_ip(T, r1, l1, l2);                        // T = k2

        // ---- acc += 2*k2 ; T = X + h/2*k2 ; boundary first, k3 halos ----
        {
            v2f a;
            a = T[6]; acc[6] = pkfma(c_two, a, acc[6]); T[6] = pkfma(c_half, a, X[6]);
            a = T[7]; acc[7] = pkfma(c_two, a, acc[7]); T[7] = pkfma(c_half, a, X[7]);
            a = T[0]; acc[0] = pkfma(c_two, a, acc[0]); T[0] = pkfma(c_half, a, X[0]);
            r1 = sh2(T[0], laneR);  r1 = atR ? swp(r1) : r1;
            l1 = sh2(T[7], laneL);  l1 = atL ? swp(l1) : l1;
            l2 = sh2(T[6], laneL);  l2 = atL ? swp(l2) : l2;
            #pragma unroll
            for (int i = 1; i < 6; ++i) {
                a = T[i]; acc[i] = pkfma(c_two, a, acc[i]); T[i] = pkfma(c_half, a, X[i]);
            }
        }
        deriv_ip(T, r1, l1, l2);                        // T = k3

        // ---- acc += 2*k3 ; T = X + h*k3 ; boundary first, k4 halos ----
        {
            v2f a;
            a = T[6]; acc[6] = pkfma(c_two, a, acc[6]); T[6] = pkfma(c_full, a, X[6]);
            a = T[7]; acc[7] = pkfma(c_two, a, acc[7]); T[7] = pkfma(c_full, a, X[7]);
            a = T[0]; acc[0] = pkfma(c_two, a, acc[0]); T[0] = pkfma(c_full, a, X[0]);
            r1 = sh2(T[0], laneR);  r1 = atR ? swp(r1) : r1;
            l1 = sh2(T[7], laneL);  l1 = atL ? swp(l1) : l1;
            l2 = sh2(T[6], laneL);  l2 = atL ? swp(l2) : l2;
            #pragma unroll
            for (int i = 1; i < 6; ++i) {
                a = T[i]; acc[i] = pkfma(c_two, a, acc[i]); T[i] = pkfma(c_full, a, X[i]);
            }
        }
        deriv_ip(T, r1, l1, l2);                        // T = k4

        // ---- X += h/6*(acc + k4) ; boundary first, next k1 halos ----
        X[6] = pkfma(c_six, acc[6] + T[6], X[6]);
        X[7] = pkfma(c_six, acc[7] + T[7], X[7]);
        X[0] = pkfma(c_six, acc[0] + T[0], X[0]);
        r1x = sh2(X[0], laneR);  r1x = atR ? swp(r1x) : r1x;
        l1x = sh2(X[7], laneL);  l1x = atL ? swp(l1x) : l1x;
        l2x = sh2(X[6], laneL);  l2x = atL ? swp(l2x) : l2x;
        #pragma unroll
        for (int i = 1; i < 6; ++i)
            X[i] = pkfma(c_six, acc[i] + T[i], X[i]);
    }

    // GEMM2 + log_softmax epilogue (packed dot over (j, j+512), wave reduce)
    float l[OUTSZ];
    #pragma unroll
    for (int o = 0; o < OUTSZ; ++o) {
        const float4* w4 = (const float4*)(W2 + (size_t)o * SYS);
        float4 wa0 = w4[lane * 2], wa1 = w4[lane * 2 + 1];
        float4 wc0 = w4[128 + lane * 2], wc1 = w4[129 + lane * 2];
        v2f s2 = mk2(0.f, 0.f);
        s2 = pkfma(X[0], mk2(wa0.x, wc0.x), s2);
        s2 = pkfma(X[1], mk2(wa0.y, wc0.y), s2);
        s2 = pkfma(X[2], mk2(wa0.z, wc0.z), s2);
        s2 = pkfma(X[3], mk2(wa0.w, wc0.w), s2);
        s2 = pkfma(X[4], mk2(wa1.x, wc1.x), s2);
        s2 = pkfma(X[5], mk2(wa1.y, wc1.y), s2);
        s2 = pkfma(X[6], mk2(wa1.z, wc1.z), s2);
        s2 = pkfma(X[7], mk2(wa1.w, wc1.w), s2);
        float s = s2.x + s2.y;
        #pragma unroll
        for (int dlt = 1; dlt < 64; dlt <<= 1) s += __shfl_xor(s, dlt);
        l[o] = s + b2[o];
    }

    float m = l[0];
    #pragma unroll
    for (int o = 1; o < OUTSZ; ++o) m = fmaxf(m, l[o]);
    float ssum = 0.f;
    #pragma unroll
    for (int o = 0; o < OUTSZ; ++o) ssum += __expf(l[o] - m);
    const float lse = m + __logf(ssum);

    float v = l[0] - lse;
    #pragma unroll
    for (int o = 1; o < OUTSZ; ++o)
        if (lane == o) v = l[o] - lse;
    if (lane < OUTSZ)
        out[(size_t)row * OUTSZ + lane] = v;
}

extern "C" void kernel_launch(void* const* d_in, const int* in_sizes, int n_in,
                              void* d_out, int out_size, void* d_ws, size_t ws_size,
                              hipStream_t stream)
{
    const float* x  = (const float*)d_in[0];
    const float* W1 = (const float*)d_in[1];
    const float* b1 = (const float*)d_in[2];
    const float* W2 = (const float*)d_in[3];
    const float* b2 = (const float*)d_in[4];
    float* out = (float*)d_out;
    float* h   = (float*)d_ws;   // 8192*1024*4 = 33.5 MB scratch

    dim3 g1(SYS / BNg, BATCH / BMg);   // 8 x 64 = 512 blocks
    gemm1_kernel<<<g1, 256, 0, stream>>>(x, W1, b1, h);

    rk4_kernel<<<BATCH / 4, 256, 0, stream>>>(h, W2, b2, out);  // 2048 blocks, 1 row/wave
}

// Round 10
// 391.763 us; speedup vs baseline: 2.8463x; 1.2118x over previous
//
#include <hip/hip_runtime.h>
#include <hip/hip_bf16.h>
#include <math.h>

#define BATCH 8192
#define INSZ 784
#define SYS 1024
#define OUTSZ 10
#define NSTEP 100
#define HSTEP 0.01f
#define FFORCE 8.0f

typedef short short8 __attribute__((ext_vector_type(8)));
typedef float float4v __attribute__((ext_vector_type(4)));
typedef float v2f __attribute__((ext_vector_type(2)));

static __device__ __forceinline__ short f2bf(float x) {
    __hip_bfloat16 b = __float2bfloat16(x);   // RNE
    return __builtin_bit_cast(short, b);
}
static __device__ __forceinline__ float bf2f(short s) {
    unsigned int u = ((unsigned int)(unsigned short)s) << 16;
    return __builtin_bit_cast(float, u);
}

static __device__ __forceinline__ v2f pkfma(v2f a, v2f b, v2f c) {
    return __builtin_elementwise_fma(a, b, c);
}
static __device__ __forceinline__ v2f mk2(float x, float y) {
    v2f r; r.x = x; r.y = y; return r;
}
// halo transport on the DS pipe (overlaps with VALU; DPP regressed — r5)
static __device__ __forceinline__ v2f sh2(v2f v, int ln) {
    v2f r; r.x = __shfl(v.x, ln); r.y = __shfl(v.y, ln); return r;
}

// ---------------------------------------------------------------------------
// GEMM1: h = x @ W1^T + b1, split-bf16 MFMA, 64x64 tile / BK=32.
// 2048 blocks -> 8 blocks/CU (8 waves/SIMD) vs r2's 512 blocks (2/SIMD).
// Each wave owns a 16x64 strip (1x4 fragments, 12 MFMA/iter).
// Staging: 4 lanes per row -> 128 B coalesced row loads; 16 elems/thread/iter.
// ---------------------------------------------------------------------------
#define BM2 64
#define BN2 64
#define BK2 32
#define LDK2 40   // shorts; 80 B row stride -> <=2-way bank alias (free, m136)

__global__ __launch_bounds__(256, 4) void gemm1_kernel(
    const float* __restrict__ x, const float* __restrict__ W1,
    const float* __restrict__ b1, float* __restrict__ h)
{
    __shared__ short Ah[BM2 * LDK2], Al[BM2 * LDK2];
    __shared__ short Bh[BN2 * LDK2], Bl[BN2 * LDK2];   // 4 * 5120 B = 20 KB

    const int t  = threadIdx.x;
    const int bm = blockIdx.y * BM2;
    const int bn = blockIdx.x * BN2;

    // staging role: 4 lanes per row, 8 contiguous k-floats per lane
    const int srow = t >> 2;          // 0..63
    const int kq   = (t & 3) * 8;     // 0,8,16,24

    // compute role
    const int wv   = t >> 6;          // wave: row strip 16*wv
    const int lane = t & 63;
    const int lm   = lane & 15;
    const int q    = lane >> 4;

    float4v acc[4];
    #pragma unroll
    for (int j = 0; j < 4; ++j) {
        acc[j][0] = 0.f; acc[j][1] = 0.f; acc[j][2] = 0.f; acc[j][3] = 0.f;
    }

    const float* xa0 = x  + (size_t)(bm + srow) * INSZ + kq;
    const float* wb0 = W1 + (size_t)(bn + srow) * INSZ + kq;

    for (int it = 0; it < 25; ++it) {
        const int k0 = it * BK2;
        {
            const bool valid = (k0 + kq) < INSZ;  // 784 % 8 == 0 -> chunk all-or-none
            float va[8], vb[8];
            if (valid) {
                #pragma unroll
                for (int p = 0; p < 2; ++p) {
                    float4 xv = ((const float4*)(xa0 + k0))[p];
                    float4 bv = ((const float4*)(wb0 + k0))[p];
                    va[4*p+0] = xv.x; va[4*p+1] = xv.y; va[4*p+2] = xv.z; va[4*p+3] = xv.w;
                    vb[4*p+0] = bv.x; vb[4*p+1] = bv.y; vb[4*p+2] = bv.z; vb[4*p+3] = bv.w;
                }
            } else {
                #pragma unroll
                for (int j = 0; j < 8; ++j) { va[j] = 0.f; vb[j] = 0.f; }
            }
            short8 ahi, alo, bhi, blo;
            #pragma unroll
            for (int j = 0; j < 8; ++j) {
                short h1 = f2bf(va[j]);
                short l1 = f2bf(va[j] - bf2f(h1));
                short h2 = f2bf(vb[j]);
                short l2 = f2bf(vb[j] - bf2f(h2));
                ahi[j] = h1;  alo[j] = l1;
                bhi[j] = h2;  blo[j] = l2;
            }
            const int base = srow * LDK2 + kq;
            *(short8*)&Ah[base] = ahi;
            *(short8*)&Al[base] = alo;
            *(short8*)&Bh[base] = bhi;
            *(short8*)&Bl[base] = blo;
        }
        __syncthreads();

        // A fragment: rows 16*wv + lm, k = q*8..q*8+7
        const int aoff = (wv * 16 + lm) * LDK2 + q * 8;
        short8 ah = *(const short8*)&Ah[aoff];
        short8 al = *(const short8*)&Al[aoff];
        #pragma unroll
        for (int fj = 0; fj < 4; ++fj) {
            const int boff = (fj * 16 + lm) * LDK2 + q * 8;
            short8 bh = *(const short8*)&Bh[boff];
            short8 bl = *(const short8*)&Bl[boff];
            acc[fj] = __builtin_amdgcn_mfma_f32_16x16x32_bf16(ah, bh, acc[fj], 0, 0, 0);
            acc[fj] = __builtin_amdgcn_mfma_f32_16x16x32_bf16(ah, bl, acc[fj], 0, 0, 0);
            acc[fj] = __builtin_amdgcn_mfma_f32_16x16x32_bf16(al, bh, acc[fj], 0, 0, 0);
        }
        __syncthreads();
    }

    // epilogue: + b1, store fp32. C/D: col = lm, row = q*4 + r.
    #pragma unroll
    for (int fj = 0; fj < 4; ++fj) {
        const int col  = bn + fj * 16 + lm;
        const float bias = b1[col];
        const int row0 = bm + wv * 16 + q * 4;
        #pragma unroll
        for (int r = 0; r < 4; ++r)
            h[(size_t)(row0 + r) * SYS + col] = acc[fj][r] + bias;
    }
}

// ---------------------------------------------------------------------------
// RK4 Lorenz-96 + GEMM2 + log_softmax — r7 version verbatim (301 us, the
// measured plateau): packed fp32, two rows per wave (pair = same element of
// rowA/rowB -> twist-free), boundary-first software-pipelined halos on the
// DS pipe. r9 (twist @8 waves) and r5 (DPP) both regressed; do not revisit.
// ---------------------------------------------------------------------------
__global__ __launch_bounds__(256, 4) void rk4_kernel(
    const float* __restrict__ hbuf, const float* __restrict__ W2,
    const float* __restrict__ b2, float* __restrict__ out)
{
    const int lane = threadIdx.x & 63;
    const int w    = threadIdx.x >> 6;
    const int rowA = blockIdx.x * 8 + w * 2;
    const int rowB = rowA + 1;

    const int laneL = (lane + 63) & 63;
    const int laneR = (lane + 1) & 63;

    v2f X[16];
    {
        const float4* a4 = (const float4*)(hbuf + (size_t)rowA * SYS) + lane * 4;
        const float4* b4 = (const float4*)(hbuf + (size_t)rowB * SYS) + lane * 4;
        #pragma unroll
        for (int k = 0; k < 4; ++k) {
            float4 av = a4[k], bv = b4[k];
            X[4*k+0] = mk2(av.x, bv.x);
            X[4*k+1] = mk2(av.y, bv.y);
            X[4*k+2] = mk2(av.z, bv.z);
            X[4*k+3] = mk2(av.w, bv.w);
        }
    }

    const v2f Fv     = mk2(FFORCE, FFORCE);
    const v2f c_half = mk2(0.5f * HSTEP, 0.5f * HSTEP);
    const v2f c_full = mk2(HSTEP, HSTEP);
    const v2f c_two  = mk2(2.0f, 2.0f);
    const v2f c_six  = mk2(HSTEP / 6.0f, HSTEP / 6.0f);

    v2f acc[16], T[16];

    // in-place deriv with pre-issued halos; interior first, DS consumers last
    auto deriv_ip = [&](v2f (&y)[16], v2f r1, v2f l1, v2f l2) {
        v2f y0o = y[0], y1o = y[1], y2o = y[2];
        v2f d0 = Fv - y[0], d1 = Fv - y[1], d15 = Fv - y[15];
        v2f p2 = y0o, p1 = y1o, cur = y[2];
        #pragma unroll
        for (int i = 2; i < 15; ++i) {
            v2f yp1 = (i < 14) ? y[i + 1] : y[15];
            v2f nv  = pkfma(yp1 - p2, p1, Fv - cur);
            p2 = p1; p1 = cur;
            if (i < 14) cur = y[i + 1];
            y[i] = nv;
        }
        y[15] = pkfma(r1 - p2, p1, d15);      // first DS consume
        y[1]  = pkfma(y2o - l1, y0o, d1);
        y[0]  = pkfma(y1o - l2, l1, d0);
    };

    // k1 halos on X
    v2f r1x = sh2(X[0],  laneR);
    v2f l1x = sh2(X[15], laneL);
    v2f l2x = sh2(X[14], laneL);

    #pragma unroll 1
    for (int s = 0; s < NSTEP; ++s) {
        // ---- k1 = deriv(X) out-of-place into acc (X intact) ----
        #pragma unroll
        for (int i = 2; i < 15; ++i)
            acc[i] = pkfma(X[i + 1] - X[i - 2], X[i - 1], Fv - X[i]);
        acc[15] = pkfma(r1x - X[13], X[14], Fv - X[15]);
        acc[1]  = pkfma(X[2] - l1x, X[0],  Fv - X[1]);
        acc[0]  = pkfma(X[1] - l2x, l1x,   Fv - X[0]);

        // ---- T = X + h/2 * k1 ; boundary first, issue k2 halos ----
        T[14] = pkfma(c_half, acc[14], X[14]);
        T[15] = pkfma(c_half, acc[15], X[15]);
        T[0]  = pkfma(c_half, acc[0],  X[0]);
        v2f r1 = sh2(T[0],  laneR);
        v2f l1 = sh2(T[15], laneL);
        v2f l2 = sh2(T[14], laneL);
        #pragma unroll
        for (int i = 1; i < 14; ++i) T[i] = pkfma(c_half, acc[i], X[i]);
        deriv_ip(T, r1, l1, l2);                        // T = k2

        // ---- acc += 2*k2 ; T = X + h/2*k2 ; boundary first, k3 halos ----
        {
            v2f a;
            a = T[14]; acc[14] = pkfma(c_two, a, acc[14]); T[14] = pkfma(c_half, a, X[14]);
            a = T[15]; acc[15] = pkfma(c_two, a, acc[15]); T[15] = pkfma(c_half, a, X[15]);
            a = T[0];  acc[0]  = pkfma(c_two, a, acc[0]);  T[0]  = pkfma(c_half, a, X[0]);
            r1 = sh2(T[0],  laneR);
            l1 = sh2(T[15], laneL);
            l2 = sh2(T[14], laneL);
            #pragma unroll
            for (int i = 1; i < 14; ++i) {
                a = T[i]; acc[i] = pkfma(c_two, a, acc[i]); T[i] = pkfma(c_half, a, X[i]);
            }
        }
        deriv_ip(T, r1, l1, l2);                        // T = k3

        // ---- acc += 2*k3 ; T = X + h*k3 ; boundary first, k4 halos ----
        {
            v2f a;
            a = T[14]; acc[14] = pkfma(c_two, a, acc[14]); T[14] = pkfma(c_full, a, X[14]);
            a = T[15]; acc[15] = pkfma(c_two, a, acc[15]); T[15] = pkfma(c_full, a, X[15]);
            a = T[0];  acc[0]  = pkfma(c_two, a, acc[0]);  T[0]  = pkfma(c_full, a, X[0]);
            r1 = sh2(T[0],  laneR);
            l1 = sh2(T[15], laneL);
            l2 = sh2(T[14], laneL);
            #pragma unroll
            for (int i = 1; i < 14; ++i) {
                a = T[i]; acc[i] = pkfma(c_two, a, acc[i]); T[i] = pkfma(c_full, a, X[i]);
            }
        }
        deriv_ip(T, r1, l1, l2);                        // T = k4

        // ---- X += h/6 * (acc + k4) ; boundary first, next k1 halos ----
        X[14] = pkfma(c_six, acc[14] + T[14], X[14]);
        X[15] = pkfma(c_six, acc[15] + T[15], X[15]);
        X[0]  = pkfma(c_six, acc[0]  + T[0],  X[0]);
        r1x = sh2(X[0],  laneR);
        l1x = sh2(X[15], laneL);
        l2x = sh2(X[14], laneL);
        #pragma unroll
        for (int i = 1; i < 14; ++i)
            X[i] = pkfma(c_six, acc[i] + T[i], X[i]);
    }

    // GEMM2 + log_softmax for both rows (x-comp = rowA, y-comp = rowB)
    v2f l[OUTSZ];
    #pragma unroll
    for (int o = 0; o < OUTSZ; ++o) {
        const float4* w4 = (const float4*)(W2 + (size_t)o * SYS) + lane * 4;
        v2f s2 = mk2(0.f, 0.f);
        #pragma unroll
        for (int k = 0; k < 4; ++k) {
            float4 wv = w4[k];
            s2 = pkfma(X[4*k+0], mk2(wv.x, wv.x), s2);
            s2 = pkfma(X[4*k+1], mk2(wv.y, wv.y), s2);
            s2 = pkfma(X[4*k+2], mk2(wv.z, wv.z), s2);
            s2 = pkfma(X[4*k+3], mk2(wv.w, wv.w), s2);
        }
        #pragma unroll
        for (int dlt = 1; dlt < 64; dlt <<= 1) {
            s2.x += __shfl_xor(s2.x, dlt);
            s2.y += __shfl_xor(s2.y, dlt);
        }
        const float bo = b2[o];
        l[o] = s2 + mk2(bo, bo);
    }

    v2f m = l[0];
    #pragma unroll
    for (int o = 1; o < OUTSZ; ++o) m = __builtin_elementwise_max(m, l[o]);
    v2f ssum = mk2(0.f, 0.f);
    #pragma unroll
    for (int o = 0; o < OUTSZ; ++o) {
        v2f d = l[o] - m;
        ssum = ssum + mk2(__expf(d.x), __expf(d.y));
    }
    const v2f lse = m + mk2(__logf(ssum.x), __logf(ssum.y));

    float vA = l[0].x - lse.x;
    float vB = l[0].y - lse.y;
    #pragma unroll
    for (int o = 1; o < OUTSZ; ++o) {
        if (lane == o) { vA = l[o].x - lse.x; vB = l[o].y - lse.y; }
    }
    if (lane < OUTSZ) {
        out[(size_t)rowA * OUTSZ + lane] = vA;
        out[(size_t)rowB * OUTSZ + lane] = vB;
    }
}

extern "C" void kernel_launch(void* const* d_in, const int* in_sizes, int n_in,
                              void* d_out, int out_size, void* d_ws, size_t ws_size,
                              hipStream_t stream)
{
    const float* x  = (const float*)d_in[0];
    const float* W1 = (const float*)d_in[1];
    const float* b1 = (const float*)d_in[2];
    const float* W2 = (const float*)d_in[3];
    const float* b2 = (const float*)d_in[4];
    float* out = (float*)d_out;
    float* h   = (float*)d_ws;   // 8192*1024*4 = 33.5 MB scratch

    dim3 g1(SYS / BN2, BATCH / BM2);   // 16 x 128 = 2048 blocks
    gemm1_kernel<<<g1, 256, 0, stream>>>(x, W1, b1, h);

    rk4_kernel<<<BATCH / 8, 256, 0, stream>>>(h, W2, b2, out);  // 1024 blocks, 2 rows/wave
}